// Round 1
// baseline (596.795 us; speedup 1.0000x reference)
//
#include <hip/hip_runtime.h>
#include <hip/hip_bf16.h>

// ---------- types ----------
typedef __attribute__((ext_vector_type(4))) float f32x4;
typedef __attribute__((ext_vector_type(8))) short bf16x8;
typedef __attribute__((ext_vector_type(4))) unsigned short u16x4;
typedef __attribute__((ext_vector_type(4))) unsigned int u32x4;

// ---------- helpers ----------
__device__ __forceinline__ unsigned short f2bf(float f) {
  unsigned int u = __builtin_bit_cast(unsigned int, f);
  unsigned int r = (u + 0x7FFFu + ((u >> 16) & 1u)) >> 16;
  return (unsigned short)r;
}
__device__ __forceinline__ float bf2f(unsigned short h) {
  unsigned int u = ((unsigned int)h) << 16;
  return __builtin_bit_cast(float, u);
}

// ---------- weight transpose + hi/lo split ----------
// W: [K,N] row-major fp32  ->  Th/Tl: [N,K] row-major bf16 bits
__global__ __launch_bounds__(256) void transpose_split(
    const float* __restrict__ W, unsigned short* __restrict__ Th,
    unsigned short* __restrict__ Tl, int K, int N) {
  __shared__ float tile[32][33];
  int n0 = blockIdx.x * 32, k0 = blockIdx.y * 32;
  int tx = threadIdx.x, ty = threadIdx.y;  // (32, 8)
#pragma unroll
  for (int r = 0; r < 4; ++r) {
    tile[ty + 8 * r][tx] = W[(size_t)(k0 + ty + 8 * r) * N + n0 + tx];
  }
  __syncthreads();
#pragma unroll
  for (int r = 0; r < 4; ++r) {
    float f = tile[tx][ty + 8 * r];  // = W[k0+tx][n0+ty+8r]
    unsigned short hi = f2bf(f);
    unsigned short lo = f2bf(f - bf2f(hi));
    size_t o = (size_t)(n0 + ty + 8 * r) * K + k0 + tx;
    Th[o] = hi;
    Tl[o] = lo;
  }
}

// ---------- bf16x3 GEMM ----------
// C[M,N] fp32 = A[M,K] fp32  @  B (given as Bt_hi/Bt_lo: [N,K] bf16)
// tile 128x128, BK=32, 256 threads = 4 waves (2x2), mfma 16x16x32 bf16.
#define BM 128
#define BN 128
#define BK 32
#define LDK 40  // padded LDS row stride (elements)

__global__ __launch_bounds__(256) void gemm_bf16x3(
    const float* __restrict__ A, const unsigned short* __restrict__ Bth,
    const unsigned short* __restrict__ Btl, float* __restrict__ C, int M,
    int N, int K) {
  __shared__ unsigned short Ah[BM][LDK];
  __shared__ unsigned short Al[BM][LDK];
  __shared__ unsigned short Bh[BN][LDK];
  __shared__ unsigned short Bl[BN][LDK];

  int tid = threadIdx.x;
  int lane = tid & 63, wid = tid >> 6;
  int wr = wid >> 1, wc = wid & 1;  // 2x2 wave grid: 64-row x 64-col per wave
  int nTilesN = N / BN;
  int bm = blockIdx.x / nTilesN, bn = blockIdx.x % nTilesN;

  const float* Ab = A + (size_t)(bm * BM) * K;
  const unsigned short* Bhb = Bth + (size_t)(bn * BN) * K;
  const unsigned short* Blb = Btl + (size_t)(bn * BN) * K;

  f32x4 acc[4][4];
#pragma unroll
  for (int i = 0; i < 4; ++i)
#pragma unroll
    for (int j = 0; j < 4; ++j) acc[i][j] = (f32x4){0.f, 0.f, 0.f, 0.f};

  // staging index precompute
  int arb = tid >> 3;          // 0..31  (A row base)
  int akk = (tid & 7) * 4;     // 0..28  (A k offset, float4)
  int bnb = tid >> 2;          // 0..63  (B row base)
  int bkk = (tid & 3) * 8;     // 0..24  (B k offset, 8 bf16 = uint4)

  int fr = lane & 15, fq = lane >> 4;

  for (int k0 = 0; k0 < K; k0 += BK) {
    __syncthreads();
    // stage A: 128x32 fp32 -> hi/lo bf16 LDS
#pragma unroll
    for (int p = 0; p < 4; ++p) {
      int row = p * 32 + arb;
      f32x4 v = *(const f32x4*)(Ab + (size_t)row * K + k0 + akk);
      u16x4 hv, lv;
#pragma unroll
      for (int i = 0; i < 4; ++i) {
        unsigned short hi = f2bf(v[i]);
        hv[i] = hi;
        lv[i] = f2bf(v[i] - bf2f(hi));
      }
      *(u16x4*)(&Ah[row][akk]) = hv;
      *(u16x4*)(&Al[row][akk]) = lv;
    }
    // stage B: straight bf16 copy of pre-split transposed weights
#pragma unroll
    for (int p = 0; p < 2; ++p) {
      int n = p * 64 + bnb;
      *(u32x4*)(&Bh[n][bkk]) = *(const u32x4*)(Bhb + (size_t)n * K + k0 + bkk);
      *(u32x4*)(&Bl[n][bkk]) = *(const u32x4*)(Blb + (size_t)n * K + k0 + bkk);
    }
    __syncthreads();

    // fragments: A row = lane&15, k = 8*(lane>>4)+j (K-contiguous in LDS)
    bf16x8 afh[4], afl[4], bfh[4], bfl[4];
#pragma unroll
    for (int i = 0; i < 4; ++i) {
      afh[i] = *(const bf16x8*)(&Ah[wr * 64 + i * 16 + fr][fq * 8]);
      afl[i] = *(const bf16x8*)(&Al[wr * 64 + i * 16 + fr][fq * 8]);
      bfh[i] = *(const bf16x8*)(&Bh[wc * 64 + i * 16 + fr][fq * 8]);
      bfl[i] = *(const bf16x8*)(&Bl[wc * 64 + i * 16 + fr][fq * 8]);
    }
#pragma unroll
    for (int mi = 0; mi < 4; ++mi)
#pragma unroll
      for (int ni = 0; ni < 4; ++ni) {
        acc[mi][ni] = __builtin_amdgcn_mfma_f32_16x16x32_bf16(
            afh[mi], bfh[ni], acc[mi][ni], 0, 0, 0);
        acc[mi][ni] = __builtin_amdgcn_mfma_f32_16x16x32_bf16(
            afh[mi], bfl[ni], acc[mi][ni], 0, 0, 0);
        acc[mi][ni] = __builtin_amdgcn_mfma_f32_16x16x32_bf16(
            afl[mi], bfh[ni], acc[mi][ni], 0, 0, 0);
      }
  }

  // epilogue: D col = lane&15, row = (lane>>4)*4 + reg
#pragma unroll
  for (int mi = 0; mi < 4; ++mi)
#pragma unroll
    for (int ni = 0; ni < 4; ++ni)
#pragma unroll
      for (int r = 0; r < 4; ++r) {
        int row = bm * BM + wr * 64 + mi * 16 + fq * 4 + r;
        int col = bn * BN + wc * 64 + ni * 16 + fr;
        C[(size_t)row * N + col] = acc[mi][ni][r];
      }
}

// ---------- masked attention ----------
// q:   [B*S, 512] fp32   (b*S+s, h*64+d)
// kv:  [B*192, 1024] fp32 (row b*192 + t*64 + n; cols 0..511 = K, 512..1023 = V)
// mask:[B*S] int32 in {0,1,2,3}
// attn:[B*S, 512] fp32
__global__ __launch_bounds__(256) void attn_kernel(
    const float* __restrict__ q, const float* __restrict__ kv,
    const int* __restrict__ mask, float* __restrict__ attn) {
  __shared__ float qls[4][512];
  __shared__ float pls[4][64];
  int wid = threadIdx.x >> 6, lane = threadIdx.x & 63;
  int g = blockIdx.x * 4 + wid;  // b*S+s
  int b = g >> 11;               // S = 2048
  int m = mask[g];
  float* arow = attn + (size_t)g * 512;
  if (m == 0) {
#pragma unroll
    for (int i = 0; i < 8; ++i) arow[lane + 64 * i] = 0.f;
    return;
  }
  int t = m - 1;
  const float* qrow = q + (size_t)g * 512;
  *(f32x4*)&qls[wid][lane * 8] = *(const f32x4*)(qrow + lane * 8);
  *(f32x4*)&qls[wid][lane * 8 + 4] = *(const f32x4*)(qrow + lane * 8 + 4);
  const float* kbase = kv + (size_t)(b * 192 + t * 64) * 1024;

  for (int h = 0; h < 8; ++h) {
    // lane j: dot(q_h, K[j])
    const float* krow = kbase + (size_t)lane * 1024 + h * 64;
    float dot = 0.f;
#pragma unroll
    for (int d = 0; d < 64; d += 4) {
      f32x4 k4 = *(const f32x4*)(krow + d);
      dot += qls[wid][h * 64 + d + 0] * k4[0];
      dot += qls[wid][h * 64 + d + 1] * k4[1];
      dot += qls[wid][h * 64 + d + 2] * k4[2];
      dot += qls[wid][h * 64 + d + 3] * k4[3];
    }
    // wave softmax over 64 lanes (reference applies no 1/sqrt(d) scaling)
    float mx = dot;
#pragma unroll
    for (int o = 32; o; o >>= 1) mx = fmaxf(mx, __shfl_xor(mx, o));
    float p = __expf(dot - mx);
    float sm = p;
#pragma unroll
    for (int o = 32; o; o >>= 1) sm += __shfl_xor(sm, o);
    p /= sm;
    pls[wid][lane] = p;
    // lane d: sum_j p_j * V[j][d]   (V loads coalesced across lanes)
    float accv = 0.f;
    const float* vcol = kbase + 512 + h * 64 + lane;
#pragma unroll 8
    for (int j = 0; j < 64; ++j) accv += pls[wid][j] * vcol[(size_t)j * 1024];
    arow[h * 64 + lane] = accv;
  }
}

// ---------- launch ----------
extern "C" void kernel_launch(void* const* d_in, const int* in_sizes, int n_in,
                              void* d_out, int out_size, void* d_ws,
                              size_t ws_size, hipStream_t stream) {
  const float* latent = (const float*)d_in[0];  // [4,3,64,2048]
  const float* y = (const float*)d_in[1];       // [4,2048,4096]
  const int* mask = (const int*)d_in[2];        // [4,2048]
  const float* W_vk = (const float*)d_in[3];    // [2048,1024]
  const float* W_q = (const float*)d_in[4];     // [4096,512]
  const float* W_out = (const float*)d_in[5];   // [512,4096]
  float* out = (float*)d_out;                   // [8192,4096]

  char* ws = (char*)d_ws;
  size_t off = 0;
  auto alloc = [&](size_t bytes) -> void* {
    void* p = ws + off;
    off = (off + bytes + 255) & ~(size_t)255;
    return p;
  };
  unsigned short* WqT_h = (unsigned short*)alloc((size_t)512 * 4096 * 2);
  unsigned short* WqT_l = (unsigned short*)alloc((size_t)512 * 4096 * 2);
  unsigned short* WvkT_h = (unsigned short*)alloc((size_t)1024 * 2048 * 2);
  unsigned short* WvkT_l = (unsigned short*)alloc((size_t)1024 * 2048 * 2);
  unsigned short* WoT_h = (unsigned short*)alloc((size_t)4096 * 512 * 2);
  unsigned short* WoT_l = (unsigned short*)alloc((size_t)4096 * 512 * 2);
  float* qbuf = (float*)alloc((size_t)8192 * 512 * 4);
  float* kvbuf = (float*)alloc((size_t)768 * 1024 * 4);
  float* attnbuf = (float*)alloc((size_t)8192 * 512 * 4);

  dim3 tb(32, 8);
  // W_q [4096,512] -> [512,4096]
  transpose_split<<<dim3(512 / 32, 4096 / 32), tb, 0, stream>>>(W_q, WqT_h,
                                                                WqT_l, 4096, 512);
  // W_vk [2048,1024] -> [1024,2048]
  transpose_split<<<dim3(1024 / 32, 2048 / 32), tb, 0, stream>>>(
      W_vk, WvkT_h, WvkT_l, 2048, 1024);
  // W_out [512,4096] -> [4096,512]
  transpose_split<<<dim3(4096 / 32, 512 / 32), tb, 0, stream>>>(
      W_out, WoT_h, WoT_l, 512, 4096);

  // kv = latent_flat[768,2048] @ W_vk -> [768,1024]
  gemm_bf16x3<<<(768 / BM) * (1024 / BN), 256, 0, stream>>>(
      latent, WvkT_h, WvkT_l, kvbuf, 768, 1024, 2048);
  // q = y[8192,4096] @ W_q -> [8192,512]
  gemm_bf16x3<<<(8192 / BM) * (512 / BN), 256, 0, stream>>>(
      y, WqT_h, WqT_l, qbuf, 8192, 512, 4096);
  // attention
  attn_kernel<<<8192 / 4, 256, 0, stream>>>(qbuf, kvbuf, mask, attnbuf);
  // out = attn[8192,512] @ W_out -> [8192,4096]
  gemm_bf16x3<<<(8192 / BM) * (4096 / BN), 256, 0, stream>>>(
      attnbuf, WoT_h, WoT_l, out, 8192, 4096, 512);
}

// Round 2
// 439.178 us; speedup vs baseline: 1.3589x; 1.3589x over previous
//
#include <hip/hip_runtime.h>
#include <hip/hip_bf16.h>

typedef __attribute__((ext_vector_type(4))) float f32x4;
typedef __attribute__((ext_vector_type(8))) short bf16x8;
typedef __attribute__((ext_vector_type(8))) unsigned short u16x8;

__device__ __forceinline__ unsigned short f2bf(float f) {
  unsigned int u = __builtin_bit_cast(unsigned int, f);
  unsigned int r = (u + 0x7FFFu + ((u >> 16) & 1u)) >> 16;
  return (unsigned short)r;
}
__device__ __forceinline__ float bf2f(unsigned short h) {
  unsigned int u = ((unsigned int)h) << 16;
  return __builtin_bit_cast(float, u);
}

__device__ __forceinline__ void gload_lds16(const void* g, void* l) {
  __builtin_amdgcn_global_load_lds(
      (__attribute__((address_space(1))) unsigned int*)g,
      (__attribute__((address_space(3))) unsigned int*)l, 16, 0, 0);
}

// ---------- fp32 -> bf16 bulk convert ----------
__global__ __launch_bounds__(256) void cvt_bf16(const float* __restrict__ in,
                                                unsigned short* __restrict__ out,
                                                long n) {
  long i = ((long)blockIdx.x * 256 + threadIdx.x) * 8;
  if (i >= n) return;
  f32x4 a = *(const f32x4*)(in + i);
  f32x4 b = *(const f32x4*)(in + i + 4);
  u16x8 o;
#pragma unroll
  for (int j = 0; j < 4; ++j) o[j] = f2bf(a[j]);
#pragma unroll
  for (int j = 0; j < 4; ++j) o[4 + j] = f2bf(b[j]);
  *(u16x8*)(out + i) = o;
}

// ---------- weight transpose + hi/lo split ----------
// W: [K,N] fp32 -> Th/Tl: [N,K] bf16 bits
__global__ __launch_bounds__(256) void transpose_split(
    const float* __restrict__ W, unsigned short* __restrict__ Th,
    unsigned short* __restrict__ Tl, int K, int N) {
  __shared__ float tile[32][33];
  int n0 = blockIdx.x * 32, k0 = blockIdx.y * 32;
  int tx = threadIdx.x, ty = threadIdx.y;  // (32, 8)
#pragma unroll
  for (int r = 0; r < 4; ++r)
    tile[ty + 8 * r][tx] = W[(size_t)(k0 + ty + 8 * r) * N + n0 + tx];
  __syncthreads();
#pragma unroll
  for (int r = 0; r < 4; ++r) {
    float f = tile[tx][ty + 8 * r];
    unsigned short hi = f2bf(f);
    unsigned short lo = f2bf(f - bf2f(hi));
    size_t o = (size_t)(n0 + ty + 8 * r) * K + k0 + tx;
    Th[o] = hi;
    Tl[o] = lo;
  }
}

// ---------- bf16x2 GEMM (A single-rounded, B split hi/lo) ----------
// C[M,N] = A[M,K](bf16) @ (Bh+Bl)[N,K]^T ; m97 structure, BK=64, gl_lds.
#define BM 128
#define BN 128
#define BK 64

template <bool OUTBF>
__global__ __launch_bounds__(256) void gemm2(
    const unsigned short* __restrict__ A, const unsigned short* __restrict__ Bh,
    const unsigned short* __restrict__ Bl, void* __restrict__ Cv, int M, int N,
    int K) {
  __shared__ unsigned short Ald[BM * BK];
  __shared__ unsigned short Bhld[BN * BK];
  __shared__ unsigned short Blld[BN * BK];
  int tid = threadIdx.x, lane = tid & 63, wid = tid >> 6;
  int wr = wid >> 1, wc = wid & 1;  // 2x2 waves, 64x64 each
  int nTN = N / BN;
  int bm = blockIdx.x / nTN, bn = blockIdx.x % nTN;
  const unsigned short* Ab = A + (size_t)(bm * BM) * K;
  const unsigned short* Bhb = Bh + (size_t)(bn * BN) * K;
  const unsigned short* Blb = Bl + (size_t)(bn * BN) * K;
  int fr = lane & 15, fq = lane >> 4;
  int srow = lane >> 3, scol = (lane & 7) * 8;

  f32x4 acc[4][4];
#pragma unroll
  for (int i = 0; i < 4; ++i)
#pragma unroll
    for (int j = 0; j < 4; ++j) acc[i][j] = (f32x4){0.f, 0.f, 0.f, 0.f};

  for (int k0 = 0; k0 < K; k0 += BK) {
    // stage: 16 chunks of 1KB per buffer; wave w owns chunks w*4..w*4+3.
#pragma unroll
    for (int i = 0; i < 4; ++i) {
      int c = wid * 4 + i;
      size_t go = (size_t)(c * 8 + srow) * K + k0 + scol;
      gload_lds16(Ab + go, &Ald[c * 512]);
      gload_lds16(Bhb + go, &Bhld[c * 512]);
      gload_lds16(Blb + go, &Blld[c * 512]);
    }
    __syncthreads();  // drains vmcnt; LDS tile ready
#pragma unroll
    for (int kk = 0; kk < 2; ++kk) {
      bf16x8 af[4], bhf[4], blf[4];
#pragma unroll
      for (int i = 0; i < 4; ++i) {
        af[i] = *(const bf16x8*)&Ald[(wr * 64 + i * 16 + fr) * BK + kk * 32 + fq * 8];
        bhf[i] = *(const bf16x8*)&Bhld[(wc * 64 + i * 16 + fr) * BK + kk * 32 + fq * 8];
        blf[i] = *(const bf16x8*)&Blld[(wc * 64 + i * 16 + fr) * BK + kk * 32 + fq * 8];
      }
#pragma unroll
      for (int mi = 0; mi < 4; ++mi)
#pragma unroll
        for (int ni = 0; ni < 4; ++ni) {
          acc[mi][ni] = __builtin_amdgcn_mfma_f32_16x16x32_bf16(
              af[mi], bhf[ni], acc[mi][ni], 0, 0, 0);
          acc[mi][ni] = __builtin_amdgcn_mfma_f32_16x16x32_bf16(
              af[mi], blf[ni], acc[mi][ni], 0, 0, 0);
        }
    }
    __syncthreads();  // protect LDS before next stage
  }

  // epilogue: D col = lane&15, row = 4*(lane>>4)+reg
#pragma unroll
  for (int mi = 0; mi < 4; ++mi)
#pragma unroll
    for (int ni = 0; ni < 4; ++ni)
#pragma unroll
      for (int r = 0; r < 4; ++r) {
        int row = bm * BM + wr * 64 + mi * 16 + fq * 4 + r;
        int col = bn * BN + wc * 64 + ni * 16 + fr;
        if constexpr (OUTBF)
          ((unsigned short*)Cv)[(size_t)row * N + col] = f2bf(acc[mi][ni][r]);
        else
          ((float*)Cv)[(size_t)row * N + col] = acc[mi][ni][r];
      }
}

// ---------- masked attention ----------
// q: [B*S,512] bf16; kv: [B*192,1024] fp32 (K|V); attn out: [B*S,512] bf16
__global__ __launch_bounds__(256) void attn_kernel(
    const unsigned short* __restrict__ q, const float* __restrict__ kv,
    const int* __restrict__ mask, unsigned short* __restrict__ attn) {
  __shared__ float qls[4][512];
  __shared__ float pls[4][64];
  int wid = threadIdx.x >> 6, lane = threadIdx.x & 63;
  int g = blockIdx.x * 4 + wid;  // b*S+s
  int b = g >> 11;               // S=2048
  int m = mask[g];
  unsigned short* arow = attn + (size_t)g * 512;
  if (m == 0) {
    u16x8 z = (u16x8){0, 0, 0, 0, 0, 0, 0, 0};
    *(u16x8*)(arow + lane * 8) = z;
    return;
  }
  int t = m - 1;
  u16x8 qv = *(const u16x8*)(q + (size_t)g * 512 + lane * 8);
#pragma unroll
  for (int j = 0; j < 8; ++j) qls[wid][lane * 8 + j] = bf2f(qv[j]);
  const float* kbase = kv + (size_t)(b * 192 + t * 64) * 1024;

  for (int h = 0; h < 8; ++h) {
    const float* krow = kbase + (size_t)lane * 1024 + h * 64;
    float dot = 0.f;
#pragma unroll
    for (int d = 0; d < 64; d += 4) {
      f32x4 k4 = *(const f32x4*)(krow + d);
      dot += qls[wid][h * 64 + d + 0] * k4[0];
      dot += qls[wid][h * 64 + d + 1] * k4[1];
      dot += qls[wid][h * 64 + d + 2] * k4[2];
      dot += qls[wid][h * 64 + d + 3] * k4[3];
    }
    float mx = dot;
#pragma unroll
    for (int o = 32; o; o >>= 1) mx = fmaxf(mx, __shfl_xor(mx, o));
    float p = __expf(dot - mx);
    float sm = p;
#pragma unroll
    for (int o = 32; o; o >>= 1) sm += __shfl_xor(sm, o);
    p /= sm;
    pls[wid][lane] = p;
    float accv = 0.f;
    const float* vcol = kbase + 512 + h * 64 + lane;
#pragma unroll 8
    for (int j = 0; j < 64; ++j) accv += pls[wid][j] * vcol[(size_t)j * 1024];
    arow[h * 64 + lane] = f2bf(accv);
  }
}

// ---------- launch ----------
extern "C" void kernel_launch(void* const* d_in, const int* in_sizes, int n_in,
                              void* d_out, int out_size, void* d_ws,
                              size_t ws_size, hipStream_t stream) {
  const float* latent = (const float*)d_in[0];  // [4,3,64,2048]
  const float* y = (const float*)d_in[1];       // [4,2048,4096]
  const int* mask = (const int*)d_in[2];        // [4,2048]
  const float* W_vk = (const float*)d_in[3];    // [2048,1024]
  const float* W_q = (const float*)d_in[4];     // [4096,512]
  const float* W_out = (const float*)d_in[5];   // [512,4096]
  float* out = (float*)d_out;                   // [8192,4096]

  char* ws = (char*)d_ws;
  size_t off = 0;
  auto alloc = [&](size_t bytes) -> void* {
    void* p = ws + off;
    off = (off + bytes + 255) & ~(size_t)255;
    return p;
  };
  unsigned short* WqT_h = (unsigned short*)alloc((size_t)512 * 4096 * 2);
  unsigned short* WqT_l = (unsigned short*)alloc((size_t)512 * 4096 * 2);
  unsigned short* WvkT_h = (unsigned short*)alloc((size_t)1024 * 2048 * 2);
  unsigned short* WvkT_l = (unsigned short*)alloc((size_t)1024 * 2048 * 2);
  unsigned short* WoT_h = (unsigned short*)alloc((size_t)4096 * 512 * 2);
  unsigned short* WoT_l = (unsigned short*)alloc((size_t)4096 * 512 * 2);
  unsigned short* ybf = (unsigned short*)alloc((size_t)8192 * 4096 * 2);
  unsigned short* latbf = (unsigned short*)alloc((size_t)768 * 2048 * 2);
  unsigned short* qbuf = (unsigned short*)alloc((size_t)8192 * 512 * 2);
  float* kvbuf = (float*)alloc((size_t)768 * 1024 * 4);
  unsigned short* attnbuf = (unsigned short*)alloc((size_t)8192 * 512 * 2);

  cvt_bf16<<<16384, 256, 0, stream>>>(y, ybf, (long)8192 * 4096);
  cvt_bf16<<<768, 256, 0, stream>>>(latent, latbf, (long)768 * 2048);

  dim3 tb(32, 8);
  transpose_split<<<dim3(16, 128), tb, 0, stream>>>(W_q, WqT_h, WqT_l, 4096, 512);
  transpose_split<<<dim3(32, 64), tb, 0, stream>>>(W_vk, WvkT_h, WvkT_l, 2048, 1024);
  transpose_split<<<dim3(128, 16), tb, 0, stream>>>(W_out, WoT_h, WoT_l, 512, 4096);

  // kv = latent[768,2048] @ W_vk -> [768,1024] fp32
  gemm2<false><<<(768 / BM) * (1024 / BN), 256, 0, stream>>>(
      latbf, WvkT_h, WvkT_l, kvbuf, 768, 1024, 2048);
  // q = y[8192,4096] @ W_q -> [8192,512] bf16
  gemm2<true><<<(8192 / BM) * (512 / BN), 256, 0, stream>>>(
      ybf, WqT_h, WqT_l, qbuf, 8192, 512, 4096);
  // attention -> [8192,512] bf16
  attn_kernel<<<8192 / 4, 256, 0, stream>>>(qbuf, kvbuf, mask, attnbuf);
  // out = attn[8192,512] @ W_out -> [8192,4096] fp32
  gemm2<false><<<(8192 / BM) * (4096 / BN), 256, 0, stream>>>(
      attnbuf, WoT_h, WoT_l, out, 8192, 4096, 512);
}